// Round 3
// baseline (43.829 us; speedup 1.0000x reference)
//
#include <hip/hip_runtime.h>

#define L 512
#define LMASK 511
#define HID 32

constexpr int THREADS        = 256;
constexpr int ROWS_PER_BLOCK = 4;
constexpr int BLOCKS_PER_B   = L / ROWS_PER_BLOCK;   // 128
constexpr int NPAIR          = HID / 2;              // 16

// d_ws layout (floats): [0, 2048) block partials, [2048, 2208) packed weights
#define WGT_OFF 2048

// Pack pre-scaled weights once: per pair p, 10 floats
// [wa0,wa1, wb0,wb1, wc0,wc1, w00,w01, w20,w21]
__global__ __launch_bounds__(64)
void prep_kernel(const float* __restrict__ W1, const float* __restrict__ b1,
                 const float* __restrict__ W2, float* __restrict__ wgt) {
    const float Kc = 2.8853900817779268f;            // 2*log2(e)
    const int h = threadIdx.x;
    if (h < HID) {
        const int p = h >> 1, q = h & 1;
        float* w = wgt + p * 10;
        w[0 + q] = Kc * W1[h * 3 + 0];
        w[2 + q] = Kc * W1[h * 3 + 1];
        w[4 + q] = Kc * W1[h * 3 + 2];
        w[6 + q] = Kc * b1[h];
        w[8 + q] = -2.0f * W2[h];                    // tanh = 1 - 2r
    }
}

__global__ __launch_bounds__(THREADS, 8)             // force VGPR <= 64
void site_kernel(const float* __restrict__ x,
                 const float* __restrict__ wgt,
                 float* __restrict__ partial) {
    const int blk = blockIdx.x;
    const int b   = blk >> 7;                        // / BLOCKS_PER_B
    const int r0  = (blk & (BLOCKS_PER_B - 1)) * ROWS_PER_BLOCK;
    const float* __restrict__ xb = x + (size_t)b * (L * L);
    const int t = threadIdx.x;

    float acc0 = 0.0f, acc1 = 0.0f;

#pragma unroll 1
    for (int g = 0; g < 2; ++g) {                    // two column groups
        const int j  = t + g * THREADS;
        const int jm = (j + LMASK) & LMASK, jp = (j + 1) & LMASK;

        // center column, rows r0-1 .. r0+4
        float cc[6];
#pragma unroll
        for (int r = 0; r < 6; ++r) {
            const int i = (r0 + r - 1 + L) & LMASK;
            cc[r] = xb[i * L + j];
        }

        // features for 4 sites (rows r0..r0+3)
        float F0[4], F1[4], F2[4];
#pragma unroll
        for (int s = 0; s < 4; ++s) {
            const int i  = r0 + s;
            const float lf = xb[i * L + jm];
            const float rg = xb[i * L + jp];
            const float c  = cc[s + 1];
            const float lr = lf + rg;                // == sx
            const float x1 = lr + cc[s] + cc[s + 2];
            float f0 = c * c, f1 = x1 * c, f2 = lr * c;
            // bound sum|f|<=50 -> |z'|<=60 -> pair product < 2^120 (finite).
            // Activates only at ~5-sigma sites where tanh is saturated anyway.
            const float m  = f0 + fabsf(f1) + fabsf(f2);
            const float sc = fminf(1.0f, 50.0f * __builtin_amdgcn_rcpf(m));
            F0[s] = f0 * sc; F1[s] = f1 * sc; F2[s] = f2 * sc;
        }

        // rolled pair loop: weights stream through ~10 regs (uniform loads)
#pragma unroll 1
        for (int p = 0; p < NPAIR; ++p) {
            const float* __restrict__ w = wgt + p * 10;
            const float wa0 = w[0], wa1 = w[1];
            const float wb0 = w[2], wb1 = w[3];
            const float wc0 = w[4], wc1 = w[5];
            const float w00 = w[6], w01 = w[7];
            const float w20 = w[8], w21 = w[9];
#pragma unroll
            for (int s = 0; s < 4; ++s) {
                const float z1 = fmaf(F0[s], wa0, fmaf(F1[s], wb0, fmaf(F2[s], wc0, w00)));
                const float z2 = fmaf(F0[s], wa1, fmaf(F1[s], wb1, fmaf(F2[s], wc1, w01)));
                const float d1 = 1.0f + __builtin_amdgcn_exp2f(z1);
                const float d2 = 1.0f + __builtin_amdgcn_exp2f(z2);
                const float un = fmaf(w20, d2, w21 * d1);  // w2a/d1+w2b/d2 = un/(d1*d2)
                const float rr = __builtin_amdgcn_rcpf(d1 * d2);
                if (s & 1) acc1 = fmaf(un, rr, acc1);
                else       acc0 = fmaf(un, rr, acc0);
            }
        }
    }

    float acc = acc0 + acc1;
#pragma unroll
    for (int off = 32; off > 0; off >>= 1)
        acc += __shfl_down(acc, off, 64);

    __shared__ float wsum[THREADS / 64];
    const int wid = t >> 6, lane = t & 63;
    if (lane == 0) wsum[wid] = acc;
    __syncthreads();
    if (t == 0)
        partial[blk] = wsum[0] + wsum[1] + wsum[2] + wsum[3];
}

// Deterministic fixed-order reduction + folded tanh constant.
__global__ __launch_bounds__(128)
void reduce_kernel(const float* __restrict__ partial,
                   const float* __restrict__ W2,
                   const float* __restrict__ b2,
                   float* __restrict__ out) {
    const int b = blockIdx.x, t = threadIdx.x;
    const float NS = (float)(L * L);                 // 262144 sites per config

    float v = partial[b * BLOCKS_PER_B + t];
    if (t < HID) v += NS * W2[t];                    // + L^2 * sum_h W2[h]
    if (t == 0)  v += NS * b2[0];                    // + L^2 * b2

#pragma unroll
    for (int off = 32; off > 0; off >>= 1)
        v += __shfl_down(v, off, 64);

    __shared__ float ws2[2];
    if ((t & 63) == 0) ws2[t >> 6] = v;
    __syncthreads();
    if (t == 0) out[b] = ws2[0] + ws2[1];
}

extern "C" void kernel_launch(void* const* d_in, const int* in_sizes, int n_in,
                              void* d_out, int out_size, void* d_ws, size_t ws_size,
                              hipStream_t stream) {
    const float* x  = (const float*)d_in[0];
    const float* W1 = (const float*)d_in[1];
    const float* b1 = (const float*)d_in[2];
    const float* W2 = (const float*)d_in[3];
    const float* b2 = (const float*)d_in[4];
    float* out      = (float*)d_out;
    float* partial  = (float*)d_ws;
    float* wgt      = (float*)d_ws + WGT_OFF;        // 8KB partials + 640B weights

    const int B = in_sizes[0] / (L * L);             // 16

    prep_kernel<<<1, 64, 0, stream>>>(W1, b1, W2, wgt);
    site_kernel<<<B * BLOCKS_PER_B, THREADS, 0, stream>>>(x, wgt, partial);
    reduce_kernel<<<B, 128, 0, stream>>>(partial, W2, b2, out);
}

// Round 4
// 42.091 us; speedup vs baseline: 1.0413x; 1.0413x over previous
//
#include <hip/hip_runtime.h>

#define L 512
#define LMASK 511
#define HID 32

constexpr int THREADS        = 256;
constexpr int ROWS_PER_BLOCK = 2;
constexpr int BLOCKS_PER_B   = L / ROWS_PER_BLOCK;   // 256
constexpr int NTAB           = 680;                  // entries; used [0, 673]
constexpr float ZCLAMP = 21.0f;                      // tanh(21/2.885)=1-1e-6
constexpr float TSCALE = 16.0f;                      // entries per unit z'
constexpr float TOFF   = 336.0f;                     // 21*16

// d_ws float layout:
//  [0, 4096)            block partials
//  [4096, 4096+128)     zw packed: 8 groups x {wa[4] wb[4] wc[4] w0[4]}
//  [4224, 4224+32)      w2 = -2*W2
//  [4256, 4256+2*NTAB)  table (s, A) pairs
#define WS_PARTIAL 0
#define WS_ZW      4096
#define WS_W2      (4096 + 128)
#define WS_TAB     (4096 + 160)

// ---- Prep: pack pre-scaled weights + build (slope,intercept) sigmoid table.
__global__ __launch_bounds__(256)
void prep_kernel(const float* __restrict__ W1, const float* __restrict__ b1,
                 const float* __restrict__ W2, float* __restrict__ ws) {
    const double Kd = 2.8853900817779268;            // 2*log2(e)
    const int t = threadIdx.x;
    if (t < HID) {
        const int g = t >> 2, q = t & 3;
        float* zw = ws + WS_ZW + g * 16;
        zw[0  + q] = (float)(Kd * (double)W1[t * 3 + 0]);
        zw[4  + q] = (float)(Kd * (double)W1[t * 3 + 1]);
        zw[8  + q] = (float)(Kd * (double)W1[t * 3 + 2]);
        zw[12 + q] = (float)(Kd * (double)b1[t]);
        ws[WS_W2 + t] = -2.0f * W2[t];
    }
    // T(z') = 1/(1+2^z'), z' = -21 + i/16.  y(uu) = s*uu + A, uu=(z'+21)*16
    for (int i = t; i < NTAB; i += 256) {
        const double u0 = -21.0 + (double)i / 16.0;
        const double v0 = 1.0 / (1.0 + exp2(u0));
        const double v1 = 1.0 / (1.0 + exp2(u0 + 0.0625));
        const double s  = v1 - v0;
        const double A  = v0 - s * (double)i;
        ws[WS_TAB + 2 * i]     = (float)s;
        ws[WS_TAB + 2 * i + 1] = (float)A;
    }
}

// ---- Stage 1: stencil + table-MLP, per-block partial sums.
__global__ __launch_bounds__(THREADS, 4)
void site_kernel(const float* __restrict__ x, const float* __restrict__ ws,
                 float* __restrict__ partial) {
    __shared__ __align__(16) float  zw_s[160];       // 128 zw + 32 w2
    __shared__ __align__(8)  float2 tab_s[NTAB];

    const int t = threadIdx.x;
    if (t < 160) zw_s[t] = ws[WS_ZW + t];
    {
        const float2* tw = (const float2*)(ws + WS_TAB);
        for (int i = t; i < NTAB; i += THREADS) tab_s[i] = tw[i];
    }
    __syncthreads();

    const int blk = blockIdx.x;
    const int b   = blk >> 8;                        // / BLOCKS_PER_B
    const int i0  = (blk & (BLOCKS_PER_B - 1)) * ROWS_PER_BLOCK;
    const float* __restrict__ xb = x + (size_t)b * (L * L);

    // 4 sites/thread: rows i0,i0+1 x cols t,t+256
    float F0[4], F1[4], F2[4];
#pragma unroll
    for (int g = 0; g < 2; ++g) {
        const int j  = t + g * THREADS;
        const int jm = (j + LMASK) & LMASK, jp = (j + 1) & LMASK;
        const int im = (i0 + LMASK) & LMASK, i1 = i0 + 1, i2 = (i0 + 2) & LMASK;

        const float cm = xb[im * L + j];
        const float c0 = xb[i0 * L + j];
        const float c1 = xb[i1 * L + j];
        const float c2 = xb[i2 * L + j];
        const float lf0 = xb[i0 * L + jm], rg0 = xb[i0 * L + jp];
        const float lf1 = xb[i1 * L + jm], rg1 = xb[i1 * L + jp];

        const float lrA = lf0 + rg0;
        const float x1A = lrA + cm + c1;
        F0[2*g]   = c0 * c0;  F1[2*g]   = x1A * c0;  F2[2*g]   = lrA * c0;

        const float lrB = lf1 + rg1;
        const float x1B = lrB + c0 + c2;
        F0[2*g+1] = c1 * c1;  F1[2*g+1] = x1B * c1;  F2[2*g+1] = lrB * c1;
    }

    float acc[4] = {0.f, 0.f, 0.f, 0.f};

#pragma unroll 2
    for (int gq = 0; gq < 8; ++gq) {                 // 4 hidden units per group
        const float4 wa  = *(const float4*)&zw_s[gq * 16 + 0];
        const float4 wb  = *(const float4*)&zw_s[gq * 16 + 4];
        const float4 wc  = *(const float4*)&zw_s[gq * 16 + 8];
        const float4 w0  = *(const float4*)&zw_s[gq * 16 + 12];
        const float4 w2v = *(const float4*)&zw_s[128 + gq * 4];
#pragma unroll
        for (int q = 0; q < 4; ++q) {
            const float waq = ((const float*)&wa)[q];
            const float wbq = ((const float*)&wb)[q];
            const float wcq = ((const float*)&wc)[q];
            const float w0q = ((const float*)&w0)[q];
            const float w2q = ((const float*)&w2v)[q];
#pragma unroll
            for (int s = 0; s < 4; ++s) {
                const float z  = fmaf(F0[s], waq, fmaf(F1[s], wbq, fmaf(F2[s], wcq, w0q)));
                const float um = fminf(fmaxf(z, -ZCLAMP), ZCLAMP);
                const float uu = fmaf(um, TSCALE, TOFF);   // in [0, 672]
                const int  idx = (int)uu;
                const float2 sa = tab_s[idx];
                const float y  = fmaf(sa.x, uu, sa.y);     // T(z') piecewise-linear
                acc[s] = fmaf(w2q, y, acc[s]);
            }
        }
    }

    float a = (acc[0] + acc[1]) + (acc[2] + acc[3]);
#pragma unroll
    for (int off = 32; off > 0; off >>= 1)
        a += __shfl_down(a, off, 64);

    __shared__ float wsum[THREADS / 64];
    const int wid = t >> 6, lane = t & 63;
    if (lane == 0) wsum[wid] = a;
    __syncthreads();
    if (t == 0)
        partial[blk] = wsum[0] + wsum[1] + wsum[2] + wsum[3];
}

// ---- Stage 2: deterministic reduction + folded tanh constant.
__global__ __launch_bounds__(THREADS)
void reduce_kernel(const float* __restrict__ partial,
                   const float* __restrict__ W2,
                   const float* __restrict__ b2,
                   float* __restrict__ out) {
    const int b = blockIdx.x, t = threadIdx.x;
    const float NS = (float)(L * L);                 // 262144 sites

    float v = partial[b * BLOCKS_PER_B + t];
    if (t < HID) v += NS * W2[t];                    // + L^2 * sum_h W2[h]
    if (t == 0)  v += NS * b2[0];                    // + L^2 * b2

#pragma unroll
    for (int off = 32; off > 0; off >>= 1)
        v += __shfl_down(v, off, 64);

    __shared__ float ws4[THREADS / 64];
    if ((t & 63) == 0) ws4[t >> 6] = v;
    __syncthreads();
    if (t == 0) out[b] = (ws4[0] + ws4[1]) + (ws4[2] + ws4[3]);
}

extern "C" void kernel_launch(void* const* d_in, const int* in_sizes, int n_in,
                              void* d_out, int out_size, void* d_ws, size_t ws_size,
                              hipStream_t stream) {
    const float* x  = (const float*)d_in[0];
    const float* W1 = (const float*)d_in[1];
    const float* b1 = (const float*)d_in[2];
    const float* W2 = (const float*)d_in[3];
    const float* b2 = (const float*)d_in[4];
    float* out      = (float*)d_out;
    float* ws       = (float*)d_ws;
    float* partial  = ws + WS_PARTIAL;

    const int B = in_sizes[0] / (L * L);             // 16

    prep_kernel<<<1, 256, 0, stream>>>(W1, b1, W2, ws);
    site_kernel<<<B * BLOCKS_PER_B, THREADS, 0, stream>>>(x, ws, partial);
    reduce_kernel<<<B, THREADS, 0, stream>>>(partial, W2, b2, out);
}

// Round 5
// 35.417 us; speedup vs baseline: 1.2375x; 1.1885x over previous
//
#include <hip/hip_runtime.h>

#define L 512
#define LMASK 511
#define HID 32

constexpr int THREADS        = 256;
constexpr int ROWS_PER_BLOCK = 4;
constexpr int BLOCKS_PER_B   = L / ROWS_PER_BLOCK;   // 128
constexpr int NTAB           = 680;                  // entries used: [0, 672]
constexpr float UCLAMP_HI    = 672.99f;

// Fused: per-block weight prep + sigmoid table build + stencil + table-MLP.
__global__ __launch_bounds__(THREADS, 4)
void site_kernel(const float* __restrict__ x,
                 const float* __restrict__ W1,
                 const float* __restrict__ b1,
                 const float* __restrict__ W2,
                 float* __restrict__ partial) {
    __shared__ __align__(16) float  zw_s[128];       // 8 groups x {wa4 wb4 wc4 w04}
    __shared__ __align__(16) float  w2_s[HID];
    __shared__ __align__(8)  float2 tab_s[NTAB];

    const int t = threadIdx.x;

    // Pre-scaled weights: uu = 16*(2log2e)*(W1.f + b1) + 336 directly from fma chain.
    if (t < HID) {
        const float K16 = 16.0f * 2.8853900817779268f;
        const int g = t >> 2, q = t & 3;
        zw_s[g * 16 +  0 + q] = K16 * W1[t * 3 + 0];
        zw_s[g * 16 +  4 + q] = K16 * W1[t * 3 + 1];
        zw_s[g * 16 +  8 + q] = K16 * W1[t * 3 + 2];
        zw_s[g * 16 + 12 + q] = fmaf(K16, b1[t], 336.0f);
        w2_s[t] = -2.0f * W2[t];                     // tanh = 1 - 2*T
    }
    // Table: entry i covers uu in [i,i+1); T(z')=1/(1+2^z'), z' = -21 + i/16.
    for (int i = t; i < NTAB; i += THREADS) {
        const float z0 = fmaf((float)i, 0.0625f, -21.0f);
        const float v0 = 1.0f / (1.0f + __builtin_amdgcn_exp2f(z0));
        const float v1 = 1.0f / (1.0f + __builtin_amdgcn_exp2f(z0 + 0.0625f));
        const float s  = v1 - v0;
        tab_s[i] = make_float2(s, fmaf(-s, (float)i, v0));
    }
    __syncthreads();

    const int blk = blockIdx.x;
    const int b   = blk >> 7;                        // / BLOCKS_PER_B
    const int i0  = (blk & (BLOCKS_PER_B - 1)) * ROWS_PER_BLOCK;
    const float* __restrict__ xb = x + (size_t)b * (L * L);

    // Features for 8 sites: rows i0..i0+3, cols t and t+256.
    float F0[8], F1[8], F2[8];
#pragma unroll
    for (int g = 0; g < 2; ++g) {
        const int j  = t + g * THREADS;
        const int jm = (j + LMASK) & LMASK, jp = (j + 1) & LMASK;

        float cc[6];                                 // center col, rows i0-1..i0+4
#pragma unroll
        for (int r = 0; r < 6; ++r) {
            const int i = (i0 + r - 1 + L) & LMASK;
            cc[r] = xb[i * L + j];
        }
#pragma unroll
        for (int s = 0; s < 4; ++s) {
            const int i   = i0 + s;
            const float lf = xb[i * L + jm];
            const float rg = xb[i * L + jp];
            const float c  = cc[s + 1];
            const float lr = lf + rg;                // == sx
            const float x1 = lr + cc[s] + cc[s + 2];
            const int k = g * 4 + s;
            F0[k] = c * c;  F1[k] = x1 * c;  F2[k] = lr * c;
        }
    }

    float acc[8] = {0.f, 0.f, 0.f, 0.f, 0.f, 0.f, 0.f, 0.f};

#pragma unroll 1
    for (int gq = 0; gq < 8; ++gq) {                 // 4 hidden units per group
        const float4 wa  = *(const float4*)&zw_s[gq * 16 + 0];
        const float4 wb  = *(const float4*)&zw_s[gq * 16 + 4];
        const float4 wc  = *(const float4*)&zw_s[gq * 16 + 8];
        const float4 w0  = *(const float4*)&zw_s[gq * 16 + 12];
        const float4 w2v = *(const float4*)&w2_s[gq * 4];
#pragma unroll
        for (int q = 0; q < 4; ++q) {
            const float waq = ((const float*)&wa)[q];
            const float wbq = ((const float*)&wb)[q];
            const float wcq = ((const float*)&wc)[q];
            const float w0q = ((const float*)&w0)[q];
            const float w2q = ((const float*)&w2v)[q];
#pragma unroll
            for (int s = 0; s < 8; ++s) {
                const float uu = fmaf(F0[s], waq, fmaf(F1[s], wbq, fmaf(F2[s], wcq, w0q)));
                const float uc = __builtin_amdgcn_fmed3f(uu, 0.0f, UCLAMP_HI);
                const int  idx = (int)uc;
                const float2 sa = tab_s[idx];
                acc[s] = fmaf(w2q, fmaf(sa.x, uc, sa.y), acc[s]);
            }
        }
    }

    float a = ((acc[0] + acc[1]) + (acc[2] + acc[3]))
            + ((acc[4] + acc[5]) + (acc[6] + acc[7]));
#pragma unroll
    for (int off = 32; off > 0; off >>= 1)
        a += __shfl_down(a, off, 64);

    __shared__ float wsum[THREADS / 64];
    const int wid = t >> 6, lane = t & 63;
    if (lane == 0) wsum[wid] = a;
    __syncthreads();
    if (t == 0)
        partial[blk] = (wsum[0] + wsum[1]) + (wsum[2] + wsum[3]);
}

// Deterministic fixed-order reduction + folded tanh constant.
__global__ __launch_bounds__(128)
void reduce_kernel(const float* __restrict__ partial,
                   const float* __restrict__ W2,
                   const float* __restrict__ b2,
                   float* __restrict__ out) {
    const int b = blockIdx.x, t = threadIdx.x;
    const float NS = (float)(L * L);                 // 262144 sites per config

    float v = partial[b * BLOCKS_PER_B + t];
    if (t < HID) v += NS * W2[t];                    // + L^2 * sum_h W2[h]
    if (t == 0)  v += NS * b2[0];                    // + L^2 * b2

#pragma unroll
    for (int off = 32; off > 0; off >>= 1)
        v += __shfl_down(v, off, 64);

    __shared__ float ws2[2];
    if ((t & 63) == 0) ws2[t >> 6] = v;
    __syncthreads();
    if (t == 0) out[b] = ws2[0] + ws2[1];
}

extern "C" void kernel_launch(void* const* d_in, const int* in_sizes, int n_in,
                              void* d_out, int out_size, void* d_ws, size_t ws_size,
                              hipStream_t stream) {
    const float* x  = (const float*)d_in[0];
    const float* W1 = (const float*)d_in[1];
    const float* b1 = (const float*)d_in[2];
    const float* W2 = (const float*)d_in[3];
    const float* b2 = (const float*)d_in[4];
    float* out      = (float*)d_out;
    float* partial  = (float*)d_ws;                  // 2048 floats

    const int B = in_sizes[0] / (L * L);             // 16

    site_kernel<<<B * BLOCKS_PER_B, THREADS, 0, stream>>>(x, W1, b1, W2, partial);
    reduce_kernel<<<B, 128, 0, stream>>>(partial, W2, b2, out);
}